// Round 5
// baseline (276.056 us; speedup 1.0000x reference)
//
#include <hip/hip_runtime.h>
#include <cstdint>
#include <cstddef>

typedef __bf16 bf16;
typedef __bf16 bf16x8 __attribute__((ext_vector_type(8)));
typedef __bf16 bf16x4 __attribute__((ext_vector_type(4)));
typedef float  f32x4  __attribute__((ext_vector_type(4)));

#define DM     1024
#define MROWS  8192   // B*L
#define LSEQ   2048
#define NHEAD  16
#define BHEADS 64     // B*H
#define KV_S   16     // L-splits for KV partial reduction (128 n per split)
#define KVT_STRIDE 4160  // 64*64 KV^T + 64 ksum

// async global->LDS, 16B per lane, LDS dest = wave-uniform base + lane*16
__device__ __forceinline__ void async16(const void* g, void* l) {
    __builtin_amdgcn_global_load_lds(
        (const __attribute__((address_space(1))) void*)g,
        (__attribute__((address_space(3))) void*)l, 16, 0, 0);
}

// ---------------- cast kernel (fp32 -> bf16), grid-stride, 7 tensors ----------------
struct CastArgs {
    const float* s[7];
    bf16*        d[7];
    int          n4[7];    // element count / 4
};

__global__ __launch_bounds__(256) void cast_all(CastArgs a) {
    const int z = blockIdx.z;
    const int n4 = a.n4[z];
    const float* __restrict__ s = a.s[z];
    bf16* __restrict__ d = a.d[z];
    for (int i = blockIdx.x * 256 + threadIdx.x; i < n4; i += 1024 * 256) {
        float4 f = ((const float4*)s)[i];
        bf16x4 o; o[0] = (bf16)f.x; o[1] = (bf16)f.y; o[2] = (bf16)f.z; o[3] = (bf16)f.w;
        ((bf16x4*)d)[i] = o;
    }
}

// ---------------- batched NT GEMM: C = A @ B^T ----------------
// A [M x 1024] bf16 row-major, B [1024 x 1024] bf16 row-major. BK=64, XOR-swizzled LDS.
// Grid fixed (8, 64, z), XCD swizzle keeps a row-stripe + B inside one XCD L2.
// mode 1: fmap (elu+1), store bf16 row-major
// mode 3: store bf16 transposed per-head  dst[((b*16+h)*64+d)*2048 + n]
// mode 4: fmap + transposed per-head
struct GemmArgs {
    const bf16* A[3];
    const bf16* B[3];
    void*       C[3];
    int         mode[3];
};

__global__ __launch_bounds__(256, 3) void gemm_nt(GemmArgs args) {
    const int z = blockIdx.z;
    const bf16* __restrict__ A  = args.A[z];
    const bf16* __restrict__ Bm = args.B[z];
    void* Cp = args.C[z];
    const int mode = args.mode[z];
    const int K = DM;

    __shared__ __attribute__((aligned(16))) bf16 sA[128 * 64];
    __shared__ __attribute__((aligned(16))) bf16 sB[128 * 64];

    const int tid  = threadIdx.x;
    const int wave = tid >> 6;
    const int lane = tid & 63;
    const int wm = wave >> 1, wn = wave & 1;

    // XCD-aware swizzle (grid x=8, y=64)
    const int fb = blockIdx.x + 8 * (int)blockIdx.y;   // 0..511
    const int bx = (fb >> 3) & 7;
    const int by = (fb & 7) * 8 + (fb >> 6);
    const int row0 = by * 128;
    const int col0 = bx * 128;

    // staging: 8 rows x 8 chunks (16B) per issue; chunk XOR-swizzled by row&7
    const int rr = lane >> 3;
    const int cc = lane & 7;
    const int csw = ((cc ^ rr) * 8);
    const bf16* gA = A  + (size_t)(row0 + wave * 32 + rr) * K + csw;
    const bf16* gB = Bm + (size_t)(col0 + wave * 32 + rr) * K + csw;

    f32x4 acc[4][4] = {};

    const int lr = lane & 15;
    const int qd = lane >> 4;
    const int swz = lr & 7;

    for (int k0 = 0; k0 < K; k0 += 64) {
        #pragma unroll
        for (int j = 0; j < 4; ++j) {
            async16(gA + k0 + (size_t)(j * 8) * K, &sA[(wave * 32 + j * 8) * 64]);
            async16(gB + k0 + (size_t)(j * 8) * K, &sB[(wave * 32 + j * 8) * 64]);
        }
        __syncthreads();

        #pragma unroll
        for (int ks = 0; ks < 2; ++ks) {
            bf16x8 af[4], bfr[4];
            #pragma unroll
            for (int mi = 0; mi < 4; ++mi)
                af[mi] = *(const bf16x8*)&sA[(wm * 64 + mi * 16 + lr) * 64 + (((ks * 4 + qd) ^ swz) * 8)];
            #pragma unroll
            for (int ni = 0; ni < 4; ++ni)
                bfr[ni] = *(const bf16x8*)&sB[(wn * 64 + ni * 16 + lr) * 64 + (((ks * 4 + qd) ^ swz) * 8)];
            #pragma unroll
            for (int mi = 0; mi < 4; ++mi)
                #pragma unroll
                for (int ni = 0; ni < 4; ++ni)
                    acc[mi][ni] = __builtin_amdgcn_mfma_f32_16x16x32_bf16(af[mi], bfr[ni], acc[mi][ni], 0, 0, 0);
        }
        __syncthreads();
    }

    if (mode >= 3) {
        // transposed per-head: 4 row-consecutive acc values -> one 8B store
        #pragma unroll
        for (int mi = 0; mi < 4; ++mi) {
            const int grow0 = row0 + wm * 64 + mi * 16 + qd * 4;
            const int b  = grow0 >> 11;
            const int n0 = grow0 & 2047;
            #pragma unroll
            for (int ni = 0; ni < 4; ++ni) {
                const int gcol = col0 + wn * 64 + ni * 16 + lr;
                const int h = gcol >> 6;
                const int d = gcol & 63;
                bf16x4 o;
                #pragma unroll
                for (int r = 0; r < 4; ++r) {
                    float val = acc[mi][ni][r];
                    if (mode == 4) val = (val > 0.f) ? (val + 1.f) : __expf(val);
                    o[r] = (bf16)val;
                }
                *(bf16x4*)&((bf16*)Cp)[(size_t)((b * 16 + h) * 64 + d) * 2048 + n0] = o;
            }
        }
    } else {
        #pragma unroll
        for (int mi = 0; mi < 4; ++mi) {
            #pragma unroll
            for (int ni = 0; ni < 4; ++ni) {
                #pragma unroll
                for (int r = 0; r < 4; ++r) {
                    const int grow = row0 + wm * 64 + mi * 16 + qd * 4 + r;
                    const int gcol = col0 + wn * 64 + ni * 16 + lr;
                    float val = acc[mi][ni][r];
                    if (mode == 1) val = (val > 0.f) ? (val + 1.f) : __expf(val);
                    ((bf16*)Cp)[(size_t)grow * DM + gcol] = (bf16)val;
                }
            }
        }
    }
}

// ---------------- final GEMM: d_out = Ab @ wob^T, fp32 out, 128x64 tiles ----------------
__global__ __launch_bounds__(256, 4) void gemm_fin(const bf16* __restrict__ A,
                                                   const bf16* __restrict__ Bm,
                                                   float* __restrict__ C) {
    const int K = DM;
    __shared__ __attribute__((aligned(16))) bf16 sA[128 * 64];
    __shared__ __attribute__((aligned(16))) bf16 sB[64 * 64];

    const int tid  = threadIdx.x;
    const int wave = tid >> 6;
    const int lane = tid & 63;
    const int wm = wave >> 1, wn = wave & 1;

    // XCD swizzle (grid x=16, y=64): each XCD owns 8 A row-stripes (2MB) + B (2MB)
    const int fb = blockIdx.x + 16 * (int)blockIdx.y;  // 0..1023
    const int xcd = fb & 7;
    const int g = fb >> 3;
    const int bx = g & 15;
    const int by = xcd * 8 + (g >> 4);
    const int row0 = by * 128;
    const int col0 = bx * 64;

    const int rr = lane >> 3;
    const int cc = lane & 7;
    const int csw = ((cc ^ rr) * 8);
    const bf16* gA = A  + (size_t)(row0 + wave * 32 + rr) * K + csw;
    const bf16* gB = Bm + (size_t)(col0 + wave * 16 + rr) * K + csw;

    f32x4 acc[4][2] = {};

    const int lr = lane & 15;
    const int qd = lane >> 4;
    const int swz = lr & 7;

    for (int k0 = 0; k0 < K; k0 += 64) {
        #pragma unroll
        for (int j = 0; j < 4; ++j)
            async16(gA + k0 + (size_t)(j * 8) * K, &sA[(wave * 32 + j * 8) * 64]);
        #pragma unroll
        for (int j = 0; j < 2; ++j)
            async16(gB + k0 + (size_t)(j * 8) * K, &sB[(wave * 16 + j * 8) * 64]);
        __syncthreads();

        #pragma unroll
        for (int ks = 0; ks < 2; ++ks) {
            bf16x8 af[4], bfr[2];
            #pragma unroll
            for (int mi = 0; mi < 4; ++mi)
                af[mi] = *(const bf16x8*)&sA[(wm * 64 + mi * 16 + lr) * 64 + (((ks * 4 + qd) ^ swz) * 8)];
            #pragma unroll
            for (int ni = 0; ni < 2; ++ni)
                bfr[ni] = *(const bf16x8*)&sB[(wn * 32 + ni * 16 + lr) * 64 + (((ks * 4 + qd) ^ swz) * 8)];
            #pragma unroll
            for (int mi = 0; mi < 4; ++mi)
                #pragma unroll
                for (int ni = 0; ni < 2; ++ni)
                    acc[mi][ni] = __builtin_amdgcn_mfma_f32_16x16x32_bf16(af[mi], bfr[ni], acc[mi][ni], 0, 0, 0);
        }
        __syncthreads();
    }

    #pragma unroll
    for (int mi = 0; mi < 4; ++mi)
        #pragma unroll
        for (int ni = 0; ni < 2; ++ni)
            #pragma unroll
            for (int r = 0; r < 4; ++r) {
                const int grow = row0 + wm * 64 + mi * 16 + qd * 4 + r;
                const int gcol = col0 + wn * 32 + ni * 16 + lr;
                C[(size_t)grow * DM + gcol] = acc[mi][ni][r];
            }
}

// ---------------- KV^T via MFMA: partial KVT[m][d] over a 128-n chunk, plus Ksum ----------------
// Inputs per-head transposed: KpT/VpT [bh][64][2048] bf16. Grid (BHEADS, KV_S=16).
__global__ __launch_bounds__(256, 4) void kv_mfma(const bf16* __restrict__ KpT,
                                                  const bf16* __restrict__ VpT,
                                                  float* __restrict__ KVTp) {
    const int bh = blockIdx.x, s = blockIdx.y;
    const int tid = threadIdx.x, wave = tid >> 6, lane = tid & 63;

    __shared__ __attribute__((aligned(16))) bf16 sVT[64 * 128];
    __shared__ __attribute__((aligned(16))) bf16 sKT[64 * 128];

    // stage 64 rows x 128 n; 4 rows (16 chunks each) per issue; slot = chunk ^ (row&7)
    #pragma unroll
    for (int j = 0; j < 4; ++j) {
        const int r  = wave * 16 + j * 4 + (lane >> 4);
        const int cg = (lane & 15) ^ (r & 7);
        const size_t gofs = (size_t)(bh * 64 + r) * 2048 + s * 128 + cg * 8;
        async16(VpT + gofs, &sVT[(wave * 16 + j * 4) * 128]);
        async16(KpT + gofs, &sKT[(wave * 16 + j * 4) * 128]);
    }
    __syncthreads();

    const int lr = lane & 15, qd = lane >> 4;
    f32x4 acc[4] = {};
    const int rA = wave * 16 + lr;
    #pragma unroll
    for (int k0 = 0; k0 < 4; ++k0) {
        const int ch = k0 * 4 + qd;
        bf16x8 a = *(const bf16x8*)&sVT[rA * 128 + ((ch ^ (rA & 7)) * 8)];
        #pragma unroll
        for (int ni = 0; ni < 4; ++ni) {
            const int rB = ni * 16 + lr;
            bf16x8 b = *(const bf16x8*)&sKT[rB * 128 + ((ch ^ (rB & 7)) * 8)];
            acc[ni] = __builtin_amdgcn_mfma_f32_16x16x32_bf16(a, b, acc[ni], 0, 0, 0);
        }
    }

    float* outp = &KVTp[(size_t)(bh * KV_S + s) * KVT_STRIDE];
    #pragma unroll
    for (int ni = 0; ni < 4; ++ni)
        #pragma unroll
        for (int r = 0; r < 4; ++r)
            outp[(wave * 16 + qd * 4 + r) * 64 + ni * 16 + lr] = acc[ni][r];

    if (wave == 0) {   // partial Ksum: lane d sums its K^T row over this n-chunk
        float ks = 0.f;
        #pragma unroll
        for (int c2 = 0; c2 < 16; ++c2) {
            bf16x8 kk = *(const bf16x8*)&sKT[lane * 128 + ((c2 ^ (lane & 7)) * 8)];
            #pragma unroll
            for (int j = 0; j < 8; ++j) ks += (float)kk[j];
        }
        outp[4096 + lane] = ks;
    }
}

// ---------------- attn out: reduces KV partials in-kernel, Z in-kernel, MFMA NT ----------------
__global__ __launch_bounds__(256, 4) void attn_out(const bf16* __restrict__ Qp,
                                                   const float* __restrict__ KVTp,
                                                   bf16* __restrict__ Ab) {
    const int bh = blockIdx.y;
    const int b = bh >> 4, h = bh & 15;
    const int row0 = blockIdx.x * 128;
    const int tid = threadIdx.x, wave = tid >> 6, lane = tid & 63;

    __shared__ __attribute__((aligned(16))) bf16 sQ[128 * 64];
    __shared__ __attribute__((aligned(16))) bf16 sKV[64 * 64];
    __shared__ float sKs[64];

    const int rr8 = lane >> 3;
    const int cc8 = lane & 7;
    const int csw = ((cc8 ^ rr8) * 8);

    // Q staging (async DMA, overlaps the partial-reduce below)
    const bf16* qbase = &Qp[(size_t)(b * LSEQ + row0) * DM + h * 64];
    #pragma unroll
    for (int j = 0; j < 4; ++j) {
        const int r0 = wave * 32 + j * 8;
        async16(qbase + (size_t)(r0 + rr8) * DM + csw, &sQ[r0 * 64]);
    }

    // reduce 16 fp32 partials -> bf16 sKV (swizzled layout) + fp32 sKs
    const float* pbase = &KVTp[(size_t)bh * KV_S * KVT_STRIDE];
    #pragma unroll
    for (int j = 0; j < 4; ++j) {
        const int idx4 = j * 256 + tid;           // float4 index 0..1023
        const int idx  = idx4 * 4;
        float4 s4 = {0.f, 0.f, 0.f, 0.f};
        #pragma unroll
        for (int p = 0; p < KV_S; ++p) {
            float4 v = *(const float4*)&pbase[(size_t)p * KVT_STRIDE + idx];
            s4.x += v.x; s4.y += v.y; s4.z += v.z; s4.w += v.w;
        }
        const int row = idx >> 6;
        const int col = idx & 63;
        bf16x4 o; o[0] = (bf16)s4.x; o[1] = (bf16)s4.y; o[2] = (bf16)s4.z; o[3] = (bf16)s4.w;
        *(bf16x4*)&sKV[row * 64 + (((col >> 3) ^ (row & 7)) * 8) + (col & 7)] = o;
    }
    if (tid < 64) {
        float ks = 0.f;
        #pragma unroll
        for (int p = 0; p < KV_S; ++p) ks += pbase[(size_t)p * KVT_STRIDE + 4096 + tid];
        sKs[tid] = ks;
    }
    __syncthreads();

    // Z: lane pair dots Q row with Ksum
    const int zrow = lane >> 1;
    const int dh = lane & 1;
    float zacc = 0.f;
    {
        const bf16* qr = &sQ[(wave * 32 + zrow) * 64];
        #pragma unroll
        for (int c = 0; c < 4; ++c) {
            const int chunk = dh * 4 + c;
            bf16x8 q8 = *(const bf16x8*)&qr[(chunk ^ (zrow & 7)) * 8];
            const float* ksp = &sKs[chunk * 8];
            #pragma unroll
            for (int j = 0; j < 8; ++j) zacc += (float)q8[j] * ksp[j];
        }
    }
    zacc += __shfl_xor(zacc, 1, 64);
    const float zinv = 1.0f / (zacc + 1e-8f);

    f32x4 acc[2][4] = {};
    const int lr = lane & 15, qd = lane >> 4;
    const int swz = lr & 7;
    #pragma unroll
    for (int ks = 0; ks < 2; ++ks) {
        bf16x8 af[2], bfr[4];
        #pragma unroll
        for (int mi = 0; mi < 2; ++mi)
            af[mi] = *(const bf16x8*)&sQ[(wave * 32 + mi * 16 + lr) * 64 + (((ks * 4 + qd) ^ swz) * 8)];
        #pragma unroll
        for (int ni = 0; ni < 4; ++ni)
            bfr[ni] = *(const bf16x8*)&sKV[(ni * 16 + lr) * 64 + (((ks * 4 + qd) ^ swz) * 8)];
        #pragma unroll
        for (int mi = 0; mi < 2; ++mi)
            #pragma unroll
            for (int ni = 0; ni < 4; ++ni)
                acc[mi][ni] = __builtin_amdgcn_mfma_f32_16x16x32_bf16(af[mi], bfr[ni], acc[mi][ni], 0, 0, 0);
    }

    #pragma unroll
    for (int mi = 0; mi < 2; ++mi) {
        #pragma unroll
        for (int rr = 0; rr < 4; ++rr) {
            const int rlocal = mi * 16 + qd * 4 + rr;
            const float zv = __shfl(zinv, rlocal * 2, 64);
            const int nrow = row0 + wave * 32 + rlocal;
            #pragma unroll
            for (int ni = 0; ni < 4; ++ni)
                Ab[(size_t)(b * LSEQ + nrow) * DM + h * 64 + ni * 16 + lr] =
                    (bf16)(acc[mi][ni][rr] * zv);
        }
    }
}

extern "C" void kernel_launch(void* const* d_in, const int* in_sizes, int n_in,
                              void* d_out, int out_size, void* d_ws, size_t ws_size,
                              hipStream_t stream) {
    const float* q  = (const float*)d_in[0];
    const float* k  = (const float*)d_in[1];
    const float* v  = (const float*)d_in[2];
    // d_in[3] = mask (all-ones, unused in linear branch)
    const float* wq = (const float*)d_in[4];
    const float* wk = (const float*)d_in[5];
    const float* wv = (const float*)d_in[6];
    const float* wo = (const float*)d_in[7];

    char* ws = (char*)d_ws;
    size_t off = 0;
    auto alloc = [&](size_t bytes) -> void* {
        void* p = ws + off;
        off += (bytes + 255) & ~(size_t)255;
        return p;
    };

    bf16* qb   = (bf16*)alloc((size_t)MROWS * DM * 2);
    bf16* kb   = (bf16*)alloc((size_t)MROWS * DM * 2);
    bf16* vb   = (bf16*)alloc((size_t)MROWS * DM * 2);
    bf16* wqb  = (bf16*)alloc((size_t)DM * DM * 2);
    bf16* wkb  = (bf16*)alloc((size_t)DM * DM * 2);
    bf16* wvb  = (bf16*)alloc((size_t)DM * DM * 2);
    bf16* wob  = (bf16*)alloc((size_t)DM * DM * 2);
    bf16* Qp   = (bf16*)alloc((size_t)MROWS * DM * 2);   // row-major [B*L][1024]
    bf16* KpT  = (bf16*)alloc((size_t)MROWS * DM * 2);   // per-head T [bh][64][2048]
    bf16* VpT  = (bf16*)alloc((size_t)MROWS * DM * 2);   // per-head T [bh][64][2048]
    bf16* Ab   = (bf16*)alloc((size_t)MROWS * DM * 2);
    float* KVTp = (float*)alloc((size_t)BHEADS * KV_S * KVT_STRIDE * 4);

    // 1. casts (grid-stride, no early-exit blocks)
    CastArgs ca;
    ca.s[0] = q;  ca.s[1] = k;  ca.s[2] = v;  ca.s[3] = wq; ca.s[4] = wk; ca.s[5] = wv; ca.s[6] = wo;
    ca.d[0] = qb; ca.d[1] = kb; ca.d[2] = vb; ca.d[3] = wqb; ca.d[4] = wkb; ca.d[5] = wvb; ca.d[6] = wob;
    const int n4_big = MROWS * DM / 4, n4_w = DM * DM / 4;
    ca.n4[0] = n4_big; ca.n4[1] = n4_big; ca.n4[2] = n4_big;
    ca.n4[3] = n4_w; ca.n4[4] = n4_w; ca.n4[5] = n4_w; ca.n4[6] = n4_w;
    cast_all<<<dim3(1024, 1, 7), 256, 0, stream>>>(ca);

    // 2. projections: Q row-major+fmap, K transposed+fmap, V transposed
    GemmArgs pa;
    pa.A[0] = qb;  pa.A[1] = kb;  pa.A[2] = vb;
    pa.B[0] = wqb; pa.B[1] = wkb; pa.B[2] = wvb;
    pa.C[0] = Qp;  pa.C[1] = KpT; pa.C[2] = VpT;
    pa.mode[0] = 1; pa.mode[1] = 4; pa.mode[2] = 3;
    gemm_nt<<<dim3(DM / 128, MROWS / 128, 3), 256, 0, stream>>>(pa);

    // 3. KV^T partials + Ksum (MFMA)
    kv_mfma<<<dim3(BHEADS, KV_S), 256, 0, stream>>>(KpT, VpT, KVTp);

    // 4. attention output (partial-reduce + Z + MFMA, fused)
    attn_out<<<dim3(LSEQ / 128, BHEADS), 256, 0, stream>>>(Qp, KVTp, Ab);

    // 5. output projection -> fp32 d_out (128x64 tiles, 1024 blocks)
    gemm_fin<<<dim3(DM / 64, MROWS / 128), 256, 0, stream>>>(Ab, wob, (float*)d_out);
}

// Round 6
// 256.574 us; speedup vs baseline: 1.0759x; 1.0759x over previous
//
#include <hip/hip_runtime.h>
#include <cstdint>
#include <cstddef>

typedef __bf16 bf16;
typedef __bf16 bf16x8 __attribute__((ext_vector_type(8)));
typedef __bf16 bf16x4 __attribute__((ext_vector_type(4)));
typedef float  f32x4  __attribute__((ext_vector_type(4)));

#define DM     1024
#define MROWS  8192   // B*L
#define LSEQ   2048
#define NHEAD  16
#define BHEADS 64     // B*H
#define KV_S   16     // L-splits for KV partial reduction (128 n per split)
#define KVT_STRIDE 4160  // 64*64 KV^T + 64 ksum

// async global->LDS, 16B per lane, LDS dest = wave-uniform base + lane*16
__device__ __forceinline__ void async16(const void* g, void* l) {
    __builtin_amdgcn_global_load_lds(
        (const __attribute__((address_space(1))) void*)g,
        (__attribute__((address_space(3))) void*)l, 16, 0, 0);
}

// ---------------- cast kernel (fp32 -> bf16), grid-stride, 7 tensors ----------------
struct CastArgs {
    const float* s[7];
    bf16*        d[7];
    int          n4[7];    // element count / 4
};

__global__ __launch_bounds__(256) void cast_all(CastArgs a) {
    const int z = blockIdx.z;
    const int n4 = a.n4[z];
    const float* __restrict__ s = a.s[z];
    bf16* __restrict__ d = a.d[z];
    for (int i = blockIdx.x * 256 + threadIdx.x; i < n4; i += 1024 * 256) {
        float4 f = ((const float4*)s)[i];
        bf16x4 o; o[0] = (bf16)f.x; o[1] = (bf16)f.y; o[2] = (bf16)f.z; o[3] = (bf16)f.w;
        ((bf16x4*)d)[i] = o;
    }
}

// ---------------- batched NT GEMM: C = A @ B^T ----------------
// A [M x 1024] bf16 row-major, B [1024 x 1024] bf16 row-major. BK=64, XOR-swizzled LDS.
// Grid fixed (8, 64, z), XCD swizzle keeps a row-stripe + B inside one XCD L2.
// mode 1: fmap (elu+1), store bf16 row-major
// mode 3: store bf16 transposed per-head  dst[((b*16+h)*64+d)*2048 + n]
// mode 4: fmap + transposed per-head
struct GemmArgs {
    const bf16* A[3];
    const bf16* B[3];
    void*       C[3];
    int         mode[3];
};

__global__ __launch_bounds__(256, 3) void gemm_nt(GemmArgs args) {
    const int z = blockIdx.z;
    const bf16* __restrict__ A  = args.A[z];
    const bf16* __restrict__ Bm = args.B[z];
    void* Cp = args.C[z];
    const int mode = args.mode[z];
    const int K = DM;

    __shared__ __attribute__((aligned(16))) bf16 sA[128 * 64];
    __shared__ __attribute__((aligned(16))) bf16 sB[128 * 64];

    const int tid  = threadIdx.x;
    const int wave = tid >> 6;
    const int lane = tid & 63;
    const int wm = wave >> 1, wn = wave & 1;

    // XCD-aware swizzle (grid x=8, y=64)
    const int fb = blockIdx.x + 8 * (int)blockIdx.y;   // 0..511
    const int bx = (fb >> 3) & 7;
    const int by = (fb & 7) * 8 + (fb >> 6);
    const int row0 = by * 128;
    const int col0 = bx * 128;

    // staging: 8 rows x 8 chunks (16B) per issue; chunk XOR-swizzled by row&7
    const int rr = lane >> 3;
    const int cc = lane & 7;
    const int csw = ((cc ^ rr) * 8);
    const bf16* gA = A  + (size_t)(row0 + wave * 32 + rr) * K + csw;
    const bf16* gB = Bm + (size_t)(col0 + wave * 32 + rr) * K + csw;

    f32x4 acc[4][4] = {};

    const int lr = lane & 15;
    const int qd = lane >> 4;
    const int swz = lr & 7;

    for (int k0 = 0; k0 < K; k0 += 64) {
        #pragma unroll
        for (int j = 0; j < 4; ++j) {
            async16(gA + k0 + (size_t)(j * 8) * K, &sA[(wave * 32 + j * 8) * 64]);
            async16(gB + k0 + (size_t)(j * 8) * K, &sB[(wave * 32 + j * 8) * 64]);
        }
        __syncthreads();

        #pragma unroll
        for (int ks = 0; ks < 2; ++ks) {
            bf16x8 af[4], bfr[4];
            #pragma unroll
            for (int mi = 0; mi < 4; ++mi)
                af[mi] = *(const bf16x8*)&sA[(wm * 64 + mi * 16 + lr) * 64 + (((ks * 4 + qd) ^ swz) * 8)];
            #pragma unroll
            for (int ni = 0; ni < 4; ++ni)
                bfr[ni] = *(const bf16x8*)&sB[(wn * 64 + ni * 16 + lr) * 64 + (((ks * 4 + qd) ^ swz) * 8)];
            #pragma unroll
            for (int mi = 0; mi < 4; ++mi)
                #pragma unroll
                for (int ni = 0; ni < 4; ++ni)
                    acc[mi][ni] = __builtin_amdgcn_mfma_f32_16x16x32_bf16(af[mi], bfr[ni], acc[mi][ni], 0, 0, 0);
        }
        __syncthreads();
    }

    if (mode >= 3) {
        // transposed per-head: 4 row-consecutive acc values -> one 8B store
        #pragma unroll
        for (int mi = 0; mi < 4; ++mi) {
            const int grow0 = row0 + wm * 64 + mi * 16 + qd * 4;
            const int b  = grow0 >> 11;
            const int n0 = grow0 & 2047;
            #pragma unroll
            for (int ni = 0; ni < 4; ++ni) {
                const int gcol = col0 + wn * 64 + ni * 16 + lr;
                const int h = gcol >> 6;
                const int d = gcol & 63;
                bf16x4 o;
                #pragma unroll
                for (int r = 0; r < 4; ++r) {
                    float val = acc[mi][ni][r];
                    if (mode == 4) val = (val > 0.f) ? (val + 1.f) : __expf(val);
                    o[r] = (bf16)val;
                }
                *(bf16x4*)&((bf16*)Cp)[(size_t)((b * 16 + h) * 64 + d) * 2048 + n0] = o;
            }
        }
    } else {
        #pragma unroll
        for (int mi = 0; mi < 4; ++mi) {
            #pragma unroll
            for (int ni = 0; ni < 4; ++ni) {
                #pragma unroll
                for (int r = 0; r < 4; ++r) {
                    const int grow = row0 + wm * 64 + mi * 16 + qd * 4 + r;
                    const int gcol = col0 + wn * 64 + ni * 16 + lr;
                    float val = acc[mi][ni][r];
                    if (mode == 1) val = (val > 0.f) ? (val + 1.f) : __expf(val);
                    ((bf16*)Cp)[(size_t)grow * DM + gcol] = (bf16)val;
                }
            }
        }
    }
}

// ---------------- final GEMM: d_out = Ab @ wob^T, fp32 out, 128x64 tiles ----------------
__global__ __launch_bounds__(256, 4) void gemm_fin(const bf16* __restrict__ A,
                                                   const bf16* __restrict__ Bm,
                                                   float* __restrict__ C) {
    const int K = DM;
    __shared__ __attribute__((aligned(16))) bf16 sA[128 * 64];
    __shared__ __attribute__((aligned(16))) bf16 sB[64 * 64];

    const int tid  = threadIdx.x;
    const int wave = tid >> 6;
    const int lane = tid & 63;
    const int wm = wave >> 1, wn = wave & 1;

    // XCD swizzle (grid x=16, y=64): each XCD owns 8 A row-stripes (2MB) + B (2MB)
    const int fb = blockIdx.x + 16 * (int)blockIdx.y;  // 0..1023
    const int xcd = fb & 7;
    const int g = fb >> 3;
    const int bx = g & 15;
    const int by = xcd * 8 + (g >> 4);
    const int row0 = by * 128;
    const int col0 = bx * 64;

    const int rr = lane >> 3;
    const int cc = lane & 7;
    const int csw = ((cc ^ rr) * 8);
    const bf16* gA = A  + (size_t)(row0 + wave * 32 + rr) * K + csw;
    const bf16* gB = Bm + (size_t)(col0 + wave * 16 + rr) * K + csw;

    f32x4 acc[4][2] = {};

    const int lr = lane & 15;
    const int qd = lane >> 4;
    const int swz = lr & 7;

    for (int k0 = 0; k0 < K; k0 += 64) {
        #pragma unroll
        for (int j = 0; j < 4; ++j)
            async16(gA + k0 + (size_t)(j * 8) * K, &sA[(wave * 32 + j * 8) * 64]);
        #pragma unroll
        for (int j = 0; j < 2; ++j)
            async16(gB + k0 + (size_t)(j * 8) * K, &sB[(wave * 16 + j * 8) * 64]);
        __syncthreads();

        #pragma unroll
        for (int ks = 0; ks < 2; ++ks) {
            bf16x8 af[4], bfr[2];
            #pragma unroll
            for (int mi = 0; mi < 4; ++mi)
                af[mi] = *(const bf16x8*)&sA[(wm * 64 + mi * 16 + lr) * 64 + (((ks * 4 + qd) ^ swz) * 8)];
            #pragma unroll
            for (int ni = 0; ni < 2; ++ni)
                bfr[ni] = *(const bf16x8*)&sB[(wn * 32 + ni * 16 + lr) * 64 + (((ks * 4 + qd) ^ swz) * 8)];
            #pragma unroll
            for (int mi = 0; mi < 4; ++mi)
                #pragma unroll
                for (int ni = 0; ni < 2; ++ni)
                    acc[mi][ni] = __builtin_amdgcn_mfma_f32_16x16x32_bf16(af[mi], bfr[ni], acc[mi][ni], 0, 0, 0);
        }
        __syncthreads();
    }

    #pragma unroll
    for (int mi = 0; mi < 4; ++mi)
        #pragma unroll
        for (int ni = 0; ni < 2; ++ni)
            #pragma unroll
            for (int r = 0; r < 4; ++r) {
                const int grow = row0 + wm * 64 + mi * 16 + qd * 4 + r;
                const int gcol = col0 + wn * 32 + ni * 16 + lr;
                C[(size_t)grow * DM + gcol] = acc[mi][ni][r];
            }
}

// ---------------- KV^T via MFMA: partial KVT[m][d] over a 128-n chunk, plus Ksum ----------------
// Inputs per-head transposed: KpT/VpT [bh][64][2048] bf16. Grid (BHEADS, KV_S=16).
__global__ __launch_bounds__(256, 4) void kv_mfma(const bf16* __restrict__ KpT,
                                                  const bf16* __restrict__ VpT,
                                                  float* __restrict__ KVTp) {
    const int bh = blockIdx.x, s = blockIdx.y;
    const int tid = threadIdx.x, wave = tid >> 6, lane = tid & 63;

    __shared__ __attribute__((aligned(16))) bf16 sVT[64 * 128];
    __shared__ __attribute__((aligned(16))) bf16 sKT[64 * 128];

    // stage 64 rows x 128 n; 4 rows (16 chunks each) per issue; slot = chunk ^ (row&7)
    #pragma unroll
    for (int j = 0; j < 4; ++j) {
        const int r  = wave * 16 + j * 4 + (lane >> 4);
        const int cg = (lane & 15) ^ (r & 7);
        const size_t gofs = (size_t)(bh * 64 + r) * 2048 + s * 128 + cg * 8;
        async16(VpT + gofs, &sVT[(wave * 16 + j * 4) * 128]);
        async16(KpT + gofs, &sKT[(wave * 16 + j * 4) * 128]);
    }
    __syncthreads();

    const int lr = lane & 15, qd = lane >> 4;
    f32x4 acc[4] = {};
    const int rA = wave * 16 + lr;
    #pragma unroll
    for (int k0 = 0; k0 < 4; ++k0) {
        const int ch = k0 * 4 + qd;
        bf16x8 a = *(const bf16x8*)&sVT[rA * 128 + ((ch ^ (rA & 7)) * 8)];
        #pragma unroll
        for (int ni = 0; ni < 4; ++ni) {
            const int rB = ni * 16 + lr;
            bf16x8 b = *(const bf16x8*)&sKT[rB * 128 + ((ch ^ (rB & 7)) * 8)];
            acc[ni] = __builtin_amdgcn_mfma_f32_16x16x32_bf16(a, b, acc[ni], 0, 0, 0);
        }
    }

    float* outp = &KVTp[(size_t)(bh * KV_S + s) * KVT_STRIDE];
    #pragma unroll
    for (int ni = 0; ni < 4; ++ni)
        #pragma unroll
        for (int r = 0; r < 4; ++r)
            outp[(wave * 16 + qd * 4 + r) * 64 + ni * 16 + lr] = acc[ni][r];

    if (wave == 0) {   // partial Ksum: lane d sums its K^T row over this n-chunk
        float ks = 0.f;
        #pragma unroll
        for (int c2 = 0; c2 < 16; ++c2) {
            bf16x8 kk = *(const bf16x8*)&sKT[lane * 128 + ((c2 ^ (lane & 7)) * 8)];
            #pragma unroll
            for (int j = 0; j < 8; ++j) ks += (float)kk[j];
        }
        outp[4096 + lane] = ks;
    }
}

// parallel reduce: grid (BHEADS, 17) — reads 17 MB of partials exactly once
__global__ __launch_bounds__(256) void kv_reduce(const float* __restrict__ KVTp,
                                                 bf16* __restrict__ KVT,
                                                 float* __restrict__ Ksum) {
    const int bh = blockIdx.x;
    const int idx = blockIdx.y * 256 + threadIdx.x;
    if (idx >= KVT_STRIDE) return;
    float s = 0.f;
    #pragma unroll
    for (int p = 0; p < KV_S; ++p) s += KVTp[(size_t)(bh * KV_S + p) * KVT_STRIDE + idx];
    if (idx < 4096) KVT[(size_t)bh * 4096 + idx] = (bf16)s;
    else            Ksum[bh * 64 + (idx - 4096)] = s;
}

// ---------------- attn out: A[n, h*64+m] = Z[n] * sum_d Q[n,d]*KVT[m,d] (MFMA NT) ----------------
// Z computed in-kernel from Ksum.
__global__ __launch_bounds__(256, 4) void attn_out(const bf16* __restrict__ Qp,
                                                   const bf16* __restrict__ KVT,
                                                   const float* __restrict__ Ksum,
                                                   bf16* __restrict__ Ab) {
    const int bh = blockIdx.y;
    const int b = bh >> 4, h = bh & 15;
    const int row0 = blockIdx.x * 128;
    const int tid = threadIdx.x, wave = tid >> 6, lane = tid & 63;

    __shared__ __attribute__((aligned(16))) bf16 sQ[128 * 64];
    __shared__ __attribute__((aligned(16))) bf16 sKV[64 * 64];
    __shared__ float sKs[64];

    const int rr8 = lane >> 3;
    const int cc8 = lane & 7;
    const int csw = ((cc8 ^ rr8) * 8);

    const bf16* qbase = &Qp[(size_t)(b * LSEQ + row0) * DM + h * 64];
    #pragma unroll
    for (int j = 0; j < 4; ++j) {
        const int r0 = wave * 32 + j * 8;
        async16(qbase + (size_t)(r0 + rr8) * DM + csw, &sQ[r0 * 64]);
    }
    const bf16* kvbase = &KVT[(size_t)bh * 4096];
    #pragma unroll
    for (int j = 0; j < 2; ++j) {
        const int r0 = wave * 16 + j * 8;
        async16(kvbase + (r0 + rr8) * 64 + csw, &sKV[r0 * 64]);
    }
    if (tid < 64) sKs[tid] = Ksum[bh * 64 + tid];
    __syncthreads();

    // Z: lane pair dots Q row with Ksum
    const int zrow = lane >> 1;
    const int dh = lane & 1;
    float zacc = 0.f;
    {
        const bf16* qr = &sQ[(wave * 32 + zrow) * 64];
        #pragma unroll
        for (int c = 0; c < 4; ++c) {
            const int chunk = dh * 4 + c;
            bf16x8 q8 = *(const bf16x8*)&qr[(chunk ^ (zrow & 7)) * 8];
            const float* ksp = &sKs[chunk * 8];
            #pragma unroll
            for (int j = 0; j < 8; ++j) zacc += (float)q8[j] * ksp[j];
        }
    }
    zacc += __shfl_xor(zacc, 1, 64);
    const float zinv = 1.0f / (zacc + 1e-8f);

    f32x4 acc[2][4] = {};
    const int lr = lane & 15, qd = lane >> 4;
    const int swz = lr & 7;
    #pragma unroll
    for (int ks = 0; ks < 2; ++ks) {
        bf16x8 af[2], bfr[4];
        #pragma unroll
        for (int mi = 0; mi < 2; ++mi)
            af[mi] = *(const bf16x8*)&sQ[(wave * 32 + mi * 16 + lr) * 64 + (((ks * 4 + qd) ^ swz) * 8)];
        #pragma unroll
        for (int ni = 0; ni < 4; ++ni)
            bfr[ni] = *(const bf16x8*)&sKV[(ni * 16 + lr) * 64 + (((ks * 4 + qd) ^ swz) * 8)];
        #pragma unroll
        for (int mi = 0; mi < 2; ++mi)
            #pragma unroll
            for (int ni = 0; ni < 4; ++ni)
                acc[mi][ni] = __builtin_amdgcn_mfma_f32_16x16x32_bf16(af[mi], bfr[ni], acc[mi][ni], 0, 0, 0);
    }

    #pragma unroll
    for (int mi = 0; mi < 2; ++mi) {
        #pragma unroll
        for (int rr = 0; rr < 4; ++rr) {
            const int rlocal = mi * 16 + qd * 4 + rr;
            const float zv = __shfl(zinv, rlocal * 2, 64);
            const int nrow = row0 + wave * 32 + rlocal;
            #pragma unroll
            for (int ni = 0; ni < 4; ++ni)
                Ab[(size_t)(b * LSEQ + nrow) * DM + h * 64 + ni * 16 + lr] =
                    (bf16)(acc[mi][ni][rr] * zv);
        }
    }
}

extern "C" void kernel_launch(void* const* d_in, const int* in_sizes, int n_in,
                              void* d_out, int out_size, void* d_ws, size_t ws_size,
                              hipStream_t stream) {
    const float* q  = (const float*)d_in[0];
    const float* k  = (const float*)d_in[1];
    const float* v  = (const float*)d_in[2];
    // d_in[3] = mask (all-ones, unused in linear branch)
    const float* wq = (const float*)d_in[4];
    const float* wk = (const float*)d_in[5];
    const float* wv = (const float*)d_in[6];
    const float* wo = (const float*)d_in[7];

    char* ws = (char*)d_ws;
    size_t off = 0;
    auto alloc = [&](size_t bytes) -> void* {
        void* p = ws + off;
        off += (bytes + 255) & ~(size_t)255;
        return p;
    };

    bf16* qb   = (bf16*)alloc((size_t)MROWS * DM * 2);
    bf16* kb   = (bf16*)alloc((size_t)MROWS * DM * 2);
    bf16* vb   = (bf16*)alloc((size_t)MROWS * DM * 2);
    bf16* wqb  = (bf16*)alloc((size_t)DM * DM * 2);
    bf16* wkb  = (bf16*)alloc((size_t)DM * DM * 2);
    bf16* wvb  = (bf16*)alloc((size_t)DM * DM * 2);
    bf16* wob  = (bf16*)alloc((size_t)DM * DM * 2);
    bf16* Qp   = (bf16*)alloc((size_t)MROWS * DM * 2);   // row-major [B*L][1024]
    bf16* KpT  = (bf16*)alloc((size_t)MROWS * DM * 2);   // per-head T [bh][64][2048]
    bf16* VpT  = (bf16*)alloc((size_t)MROWS * DM * 2);   // per-head T [bh][64][2048]
    bf16* Ab   = (bf16*)alloc((size_t)MROWS * DM * 2);
    float* KVTp = (float*)alloc((size_t)BHEADS * KV_S * KVT_STRIDE * 4);
    bf16* KVT  = (bf16*)alloc((size_t)BHEADS * 4096 * 2);
    float* Ksum = (float*)alloc((size_t)BHEADS * 64 * 4);

    // 1. casts (grid-stride, no early-exit blocks)
    CastArgs ca;
    ca.s[0] = q;  ca.s[1] = k;  ca.s[2] = v;  ca.s[3] = wq; ca.s[4] = wk; ca.s[5] = wv; ca.s[6] = wo;
    ca.d[0] = qb; ca.d[1] = kb; ca.d[2] = vb; ca.d[3] = wqb; ca.d[4] = wkb; ca.d[5] = wvb; ca.d[6] = wob;
    const int n4_big = MROWS * DM / 4, n4_w = DM * DM / 4;
    ca.n4[0] = n4_big; ca.n4[1] = n4_big; ca.n4[2] = n4_big;
    ca.n4[3] = n4_w; ca.n4[4] = n4_w; ca.n4[5] = n4_w; ca.n4[6] = n4_w;
    cast_all<<<dim3(1024, 1, 7), 256, 0, stream>>>(ca);

    // 2. projections: Q row-major+fmap, K transposed+fmap, V transposed
    GemmArgs pa;
    pa.A[0] = qb;  pa.A[1] = kb;  pa.A[2] = vb;
    pa.B[0] = wqb; pa.B[1] = wkb; pa.B[2] = wvb;
    pa.C[0] = Qp;  pa.C[1] = KpT; pa.C[2] = VpT;
    pa.mode[0] = 1; pa.mode[1] = 4; pa.mode[2] = 3;
    gemm_nt<<<dim3(DM / 128, MROWS / 128, 3), 256, 0, stream>>>(pa);

    // 3. KV^T partials + Ksum (MFMA), then one-pass reduce
    kv_mfma<<<dim3(BHEADS, KV_S), 256, 0, stream>>>(KpT, VpT, KVTp);
    kv_reduce<<<dim3(BHEADS, (KVT_STRIDE + 255) / 256), 256, 0, stream>>>(KVTp, KVT, Ksum);

    // 4. attention output (Z in-kernel)
    attn_out<<<dim3(LSEQ / 128, BHEADS), 256, 0, stream>>>(Qp, KVT, Ksum, Ab);

    // 5. output projection -> fp32 d_out (128x64 tiles, 1024 blocks)
    gemm_fin<<<dim3(DM / 64, MROWS / 128), 256, 0, stream>>>(Ab, wob, (float*)d_out);
}